// Round 2
// 212.197 us; speedup vs baseline: 1.0593x; 1.0593x over previous
//
#include <hip/hip_runtime.h>
#include <hip/hip_bf16.h>

typedef __attribute__((ext_vector_type(4))) float f32x4;
typedef __attribute__((ext_vector_type(8))) short s16x8;

#define NROWS 4096
#define DMODEL 256
#define NHEAD 8
#define HDIM 32
#define PSTRIDE 72     // attn P-scratch row: 144 B, 16B-aligned
#define OSTRIDE 33     // attn sO row
#define M2C 24.0f      // fixed softmax max (log2 domain)
#define NM (NROWS * DMODEL)
// mega-kernel LDS strides
#define SH_S 268
#define SY_S 264
#define SR_S 520

__device__ __forceinline__ short bf16r(float f) {
    union { float f; unsigned u; } v; v.f = f;
    unsigned r = v.u + 0x7fffu + ((v.u >> 16) & 1u);  // RNE
    return (short)(r >> 16);
}

__device__ __forceinline__ float fexp2(float x) {
    float r;
    asm("v_exp_f32 %0, %1" : "=v"(r) : "v"(x));
    return r;
}

__device__ __forceinline__ unsigned pk_bf16(float a, float b) {
#if __has_builtin(__builtin_amdgcn_cvt_pk_bf16_f32)
    typedef __bf16 bf2 __attribute__((ext_vector_type(2)));
    union { bf2 h; unsigned u; } c;
    c.h = __builtin_amdgcn_cvt_pk_bf16_f32(a, b);
    return c.u;
#else
    return (unsigned)(unsigned short)bf16r(a) | ((unsigned)(unsigned short)bf16r(b) << 16);
#endif
}

__device__ __forceinline__ s16x8 pack8(float4 a, float4 b) {
    s16x8 r;
    r[0] = bf16r(a.x); r[1] = bf16r(a.y); r[2] = bf16r(a.z); r[3] = bf16r(a.w);
    r[4] = bf16r(b.x); r[5] = bf16r(b.y); r[6] = bf16r(b.z); r[7] = bf16r(b.w);
    return r;
}

// ---------------------------------------------------------------------------
// Dispatch 1: adj -> bitmask [0,2048); pack Wo/W1/W2 [2048,2208);
// pack Wq/Wk/Wv [2208,2304); pack X [2304,2816). All one-shot streaming.
__global__ __launch_bounds__(256) void prep1_kernel(
        const int* __restrict__ adj, unsigned* __restrict__ mask,
        const float* __restrict__ Wo, const float* __restrict__ W1,
        const float* __restrict__ W2, short* __restrict__ Wb,
        const float* __restrict__ Wq, const float* __restrict__ Wk,
        const float* __restrict__ Wv, short* __restrict__ Wqkvb,
        const float* __restrict__ X, short* __restrict__ Xb) {
    const int b = blockIdx.x;
    const int tid = threadIdx.x;
    const int lane = tid & 63;
    if (b < 2048) {
        const int waveid = b * 4 + (tid >> 6);          // 0..8191
        int4 av[8];
        int rows[8], segs[8];
#pragma unroll
        for (int i = 0; i < 8; ++i) {
            const int task = waveid + i * 8192;          // 0..65535
            rows[i] = task >> 4; segs[i] = task & 15;
            av[i] = *(const int4*)(adj + (size_t)rows[i] * NROWS + segs[i] * 256 + lane * 4);
        }
#pragma unroll
        for (int i = 0; i < 8; ++i) {
            const int row = rows[i];
            const int c0 = segs[i] * 256 + lane * 4;
            unsigned nib = (unsigned)(av[i].x > 0 || c0 == row)
                         | ((unsigned)(av[i].y > 0 || c0 + 1 == row) << 1)
                         | ((unsigned)(av[i].z > 0 || c0 + 2 == row) << 2)
                         | ((unsigned)(av[i].w > 0 || c0 + 3 == row) << 3);
            unsigned v = nib << ((lane & 7) * 4);
            v |= __shfl_xor((int)v, 1, 64);
            v |= __shfl_xor((int)v, 2, 64);
            v |= __shfl_xor((int)v, 4, 64);
            if ((lane & 7) == 0)
                mask[row * 128 + segs[i] * 8 + (lane >> 3)] = v;
        }
    } else if (b < 2208) {
        int i = (b - 2048) * 2048 + tid * 8;
        const float* src; int off;
        if (i < 65536)       { src = Wo; off = i; }
        else if (i < 196608) { src = W1; off = i - 65536; }
        else                 { src = W2; off = i - 196608; }
        *(s16x8*)(Wb + i) = pack8(*(const float4*)(src + off), *(const float4*)(src + off + 4));
    } else if (b < 2304) {
        int i = (b - 2208) * 2048 + tid * 8;
        const float* src; int off;
        if (i < 65536)       { src = Wq; off = i; }
        else if (i < 131072) { src = Wk; off = i - 65536; }
        else                 { src = Wv; off = i - 131072; }
        *(s16x8*)(Wqkvb + i) = pack8(*(const float4*)(src + off), *(const float4*)(src + off + 4));
    } else {
        int i = (b - 2304) * 2048 + tid * 8;
        *(s16x8*)(Xb + i) = pack8(*(const float4*)(X + i), *(const float4*)(X + i + 4));
    }
}

// ---------------------------------------------------------------------------
// Dispatch 2: QKV GEMM from pre-packed bf16 X and [Wq;Wk;Wv]; V written
// PRE-SWIZZLED in 16x16 MFMA A-frag order (identical layout to baseline).
__global__ __launch_bounds__(256) void prep2_kernel(
        const short* __restrict__ Xb, const short* __restrict__ Wqkvb,
        const float* __restrict__ bq, const float* __restrict__ bk,
        const float* __restrict__ bv,
        short* __restrict__ Qb, short* __restrict__ Kb,
        short* __restrict__ Vswz) {
    __shared__ short sT[64 * 72];   // V-tile staging [hd_local][key_local]
    const int b = blockIdx.x;
    const int tid = threadIdx.x;
    const int lane = tid & 63;
    const int wv = tid >> 6;
    const int quad = lane >> 4, col = lane & 15;
    const int bx = b & 63, by = b >> 6;           // by 0..11
    const int o0 = by * 64;                        // 0..704 (row into [Wq;Wk;Wv])
    const int z = o0 >> 8;
    const float* bias = (z == 0) ? bq : (z == 1 ? bk : bv);
    const int ow0 = o0 & 255;
    const int n0 = bx * 64 + wv * 16;
    const float QSC = 0.25505653437397888f;        // log2e / sqrt(32)

    f32x4 zero = {0.f, 0.f, 0.f, 0.f};
    f32x4 acc[4] = {zero, zero, zero, zero};
    const short* ap = Xb + (size_t)(n0 + col) * DMODEL + quad * 8;
#pragma unroll
    for (int k0 = 0; k0 < DMODEL; k0 += 32) {
        s16x8 af = *(const s16x8*)(ap + k0);
#pragma unroll
        for (int t = 0; t < 4; ++t) {
            s16x8 bf = *(const s16x8*)(Wqkvb + (size_t)(o0 + t * 16 + col) * DMODEL + quad * 8 + k0);
            acc[t] = __builtin_amdgcn_mfma_f32_16x16x32_bf16(af, bf, acc[t], 0, 0, 0);
        }
    }
    if (z != 2) {
#pragma unroll
        for (int t = 0; t < 4; ++t) {
            const int oo = ow0 + t * 16 + col;
            float bvv = bias[oo];
#pragma unroll
            for (int r = 0; r < 4; ++r) {
                int n = n0 + quad * 4 + r;
                float v = acc[t][r] + bvv;
                if (z == 0) Qb[(size_t)n * DMODEL + oo] = bf16r(v * QSC);
                else        Kb[(size_t)(oo >> 5) * NROWS * HDIM + (size_t)n * HDIM + (oo & 31)] = bf16r(v);
            }
        }
    } else {
        // V: stage [hd_local 0..63][key_local 0..63] tile in LDS.
#pragma unroll
        for (int t = 0; t < 4; ++t) {
            const int oot = t * 16 + col;
            float bvv = bias[ow0 + oot];
#pragma unroll
            for (int r = 0; r < 4; ++r) {
                int nn = wv * 16 + quad * 4 + r;
                sT[oot * 72 + nn] = bf16r(acc[t][r] + bvv);
            }
        }
        __syncthreads();
        // Emit swizzled frags: frag f = (lh, hdh, kh); element (lane L, j)
        // = V^T[lh*32+hdh*16+(L&15)][kh*32+(L>>4)*8+j].
        const int f = tid >> 5;                 // 0..7
        const int lh = f >> 2, hdh = (f >> 1) & 1, kh = f & 1;
        const int L0 = (tid & 31) * 2;
        const int hgl = (ow0 >> 5) + lh;        // global head
        short* dst = Vswz + (((size_t)(hgl * 64 + bx) * 4 + hdh * 2 + kh) * 512);
#pragma unroll
        for (int e = 0; e < 2; ++e) {
            int L = L0 + e;
            int hd_local = lh * 32 + hdh * 16 + (L & 15);
            int key_local = kh * 32 + ((L >> 4) * 8);
            s16x8 v = *(const s16x8*)&sT[hd_local * 72 + key_local];
            *(s16x8*)(dst + L * 8) = v;
        }
    }
}

// ---------------------------------------------------------------------------
// Dispatch 3: flash attention (known-good 16x16 structure). Block = (32 q,
// head), grid 1024; wave w owns keys [w*1024, +1024), 16 iters of 64 keys.
// Masking via 16-entry LDS LUT on packed bf16 pairs (exact-equivalent to
// per-element cndmask, ~2.5x fewer VALU ops).
__global__ __launch_bounds__(256) void attn_kernel(const short* __restrict__ Qb,
                                                   const short* __restrict__ Kb,
                                                   const short* __restrict__ Vswz,
                                                   const unsigned* __restrict__ mask,
                                                   short* __restrict__ Om) {
    __shared__ union {
        short sP[2][16 * PSTRIDE];
        float sO[HDIM][OSTRIDE];
    } u[4];
    __shared__ float sl[4][32];
    __shared__ __align__(16) unsigned lut2[32];  // [nib][2]: AND masks for 2 packed pairs

    const int tid = threadIdx.x;
    const int wv = tid >> 6, lane = tid & 63;
    const int quad = lane >> 4, col = lane & 15;
    const int h = blockIdx.x & 7;
    const int q0 = (blockIdx.x >> 3) * 32;
    const int kw = wv * 1024;

    if (tid < 32) {
        int i = tid >> 1;
        unsigned b0 = (tid & 1) ? ((i >> 2) & 1u) : (i & 1u);
        unsigned b1 = (tid & 1) ? ((i >> 3) & 1u) : ((i >> 1) & 1u);
        lut2[tid] = (b0 ? 0xFFFFu : 0u) | (b1 ? 0xFFFF0000u : 0u);
    }
    __syncthreads();

    s16x8 qf[2];
    qf[0] = *(const s16x8*)(Qb + (size_t)(q0 + col) * DMODEL + h * HDIM + quad * 8);
    qf[1] = *(const s16x8*)(Qb + (size_t)(q0 + 16 + col) * DMODEL + h * HDIM + quad * 8);

    const short* kp = Kb + (size_t)h * NROWS * HDIM + (size_t)(kw + col) * HDIM + quad * 8;
    const short* vbase = Vswz + ((size_t)(h * 64 + (kw >> 6)) * 4) * 512 + lane * 8;
    const unsigned* mp0 = mask + (size_t)(q0 + col) * 128 + (kw >> 5);
    const unsigned* mp1 = mp0 + 16 * 128;

    const short onev = (col == 0) ? (short)0x3F80 : (short)0;
    const s16x8 ones = {onev, onev, onev, onev, onev, onev, onev, onev};

    f32x4 zero = {0.f, 0.f, 0.f, 0.f};
    f32x4 acc[2][2] = {{zero, zero}, {zero, zero}};
    f32x4 lacc[2] = {zero, zero};
    const f32x4 cinit = {-M2C, -M2C, -M2C, -M2C};
    const int sh_lo = quad * 4, sh_hi = 16 + quad * 4;
    const char* lb = (const char*)lut2;

#pragma unroll 2
    for (int it = 0; it < 16; ++it) {
        const short* k = kp + it * 64 * HDIM;
        s16x8 kf0 = *(const s16x8*)(k);
        s16x8 kf1 = *(const s16x8*)(k + 16 * HDIM);
        s16x8 kf2 = *(const s16x8*)(k + 32 * HDIM);
        s16x8 kf3 = *(const s16x8*)(k + 48 * HDIM);
        uint2 w0 = *(const uint2*)(mp0 + it * 2);
        uint2 w1 = *(const uint2*)(mp1 + it * 2);
        const short* vb = vbase + it * 4 * 512;
        s16x8 vf00 = *(const s16x8*)(vb);             // hd 0-15,  keys 0-31
        s16x8 vf01 = *(const s16x8*)(vb + 512);       // hd 0-15,  keys 32-63
        s16x8 vf10 = *(const s16x8*)(vb + 1024);      // hd 16-31, keys 0-31
        s16x8 vf11 = *(const s16x8*)(vb + 1536);      // hd 16-31, keys 32-63

#pragma unroll
        for (int qs = 0; qs < 2; ++qs) {
            const unsigned wx = qs ? w1.x : w0.x;     // keys 0..31 of tile
            const unsigned wy = qs ? w1.y : w0.y;     // keys 32..63
            // LUT AND-masks: st[t][r] = key t*16 + quad*4 + r
            uint2 m0 = *(const uint2*)(lb + (((wx >> sh_lo) & 0xF) << 3));
            uint2 m1 = *(const uint2*)(lb + (((wx >> sh_hi) & 0xF) << 3));
            uint2 m2 = *(const uint2*)(lb + (((wy >> sh_lo) & 0xF) << 3));
            uint2 m3 = *(const uint2*)(lb + (((wy >> sh_hi) & 0xF) << 3));

            f32x4 st[4];
            st[0] = __builtin_amdgcn_mfma_f32_16x16x32_bf16(kf0, qf[qs], cinit, 0, 0, 0);
            st[1] = __builtin_amdgcn_mfma_f32_16x16x32_bf16(kf1, qf[qs], cinit, 0, 0, 0);
            st[2] = __builtin_amdgcn_mfma_f32_16x16x32_bf16(kf2, qf[qs], cinit, 0, 0, 0);
            st[3] = __builtin_amdgcn_mfma_f32_16x16x32_bf16(kf3, qf[qs], cinit, 0, 0, 0);

            short* pb = &u[wv].sP[qs][0];
            uint2 pr;
            pr.x = pk_bf16(fexp2(st[0][0]), fexp2(st[0][1])) & m0.x;
            pr.y = pk_bf16(fexp2(st[0][2]), fexp2(st[0][3])) & m0.y;
            *(uint2*)(pb + col * PSTRIDE + 0 * 16 + quad * 4) = pr;
            pr.x = pk_bf16(fexp2(st[1][0]), fexp2(st[1][1])) & m1.x;
            pr.y = pk_bf16(fexp2(st[1][2]), fexp2(st[1][3])) & m1.y;
            *(uint2*)(pb + col * PSTRIDE + 1 * 16 + quad * 4) = pr;
            pr.x = pk_bf16(fexp2(st[2][0]), fexp2(st[2][1])) & m2.x;
            pr.y = pk_bf16(fexp2(st[2][2]), fexp2(st[2][3])) & m2.y;
            *(uint2*)(pb + col * PSTRIDE + 2 * 16 + quad * 4) = pr;
            pr.x = pk_bf16(fexp2(st[3][0]), fexp2(st[3][1])) & m3.x;
            pr.y = pk_bf16(fexp2(st[3][2]), fexp2(st[3][3])) & m3.y;
            *(uint2*)(pb + col * PSTRIDE + 3 * 16 + quad * 4) = pr;

            s16x8 pb0 = *(const s16x8*)(pb + col * PSTRIDE + quad * 8);
            s16x8 pb1 = *(const s16x8*)(pb + col * PSTRIDE + 32 + quad * 8);

            acc[qs][0] = __builtin_amdgcn_mfma_f32_16x16x32_bf16(vf00, pb0, acc[qs][0], 0, 0, 0);
            acc[qs][0] = __builtin_amdgcn_mfma_f32_16x16x32_bf16(vf01, pb1, acc[qs][0], 0, 0, 0);
            acc[qs][1] = __builtin_amdgcn_mfma_f32_16x16x32_bf16(vf10, pb0, acc[qs][1], 0, 0, 0);
            acc[qs][1] = __builtin_amdgcn_mfma_f32_16x16x32_bf16(vf11, pb1, acc[qs][1], 0, 0, 0);
            lacc[qs] = __builtin_amdgcn_mfma_f32_16x16x32_bf16(ones, pb0, lacc[qs], 0, 0, 0);
            lacc[qs] = __builtin_amdgcn_mfma_f32_16x16x32_bf16(ones, pb1, lacc[qs], 0, 0, 0);
        }
    }

#pragma unroll
    for (int qs = 0; qs < 2; ++qs) {
        if (lane < 16) sl[wv][qs * 16 + col] = lacc[qs][0];
#pragma unroll
        for (int rr = 0; rr < 4; ++rr) {
            u[wv].sO[quad * 4 + rr][qs * 16 + col]      = acc[qs][0][rr];
            u[wv].sO[16 + quad * 4 + rr][qs * 16 + col] = acc[qs][1][rr];
        }
    }
    __syncthreads();

    // merge the 4 key-partitions, normalize, write bf16
    const int q = tid >> 3, hd0 = (tid & 7) * 4;
    float l = sl[0][q] + sl[1][q] + sl[2][q] + sl[3][q];
    float inv = 1.f / l;   // diagonal always allowed -> l > 0
    float4 ov;
    ov.x = u[0].sO[hd0][q]     + u[1].sO[hd0][q]     + u[2].sO[hd0][q]     + u[3].sO[hd0][q];
    ov.y = u[0].sO[hd0 + 1][q] + u[1].sO[hd0 + 1][q] + u[2].sO[hd0 + 1][q] + u[3].sO[hd0 + 1][q];
    ov.z = u[0].sO[hd0 + 2][q] + u[1].sO[hd0 + 2][q] + u[2].sO[hd0 + 2][q] + u[3].sO[hd0 + 2][q];
    ov.w = u[0].sO[hd0 + 3][q] + u[1].sO[hd0 + 3][q] + u[2].sO[hd0 + 3][q] + u[3].sO[hd0 + 3][q];
    uint2 ob;
    ob.x = pk_bf16(ov.x * inv, ov.y * inv);
    ob.y = pk_bf16(ov.z * inv, ov.w * inv);
    *(uint2*)(Om + (size_t)(q0 + q) * DMODEL + h * HDIM + hd0) = ob;
}

// ---------------------------------------------------------------------------
// Dispatch 4: post-attention chain per 16-row stripe, 512 threads/block.
__global__ __launch_bounds__(512) void mega_kernel(
        const short* __restrict__ Omb,
        const float* __restrict__ X,
        const short* __restrict__ Wob, const short* __restrict__ W1b,
        const short* __restrict__ W2b,
        const float* __restrict__ bo,
        const float* __restrict__ g1, const float* __restrict__ be1,
        const float* __restrict__ b1, const float* __restrict__ b2,
        const float* __restrict__ g2, const float* __restrict__ be2,
        float* __restrict__ out) {
    __shared__ short sR[16 * SR_S];
    __shared__ float sH[16 * SH_S];
    __shared__ short sY[16 * SY_S];

    const int tid = threadIdx.x;
    const int wv = tid >> 6, lane = tid & 63;
    const int quad = lane >> 4, col = lane & 15;
    const int n0 = blockIdx.x * 16;
    const int rr_ = tid >> 5, c8 = (tid & 31) * 8;
    const int n_ln = n0 + rr_;
    f32x4 zero = {0.f, 0.f, 0.f, 0.f};

    // ---- Stage A2: h = O · Wo^T + bo (wave: 16 x 32; A from global) ----
    {
        const int o0 = wv * 32;
        f32x4 acc[2] = {zero, zero};
#pragma unroll
        for (int k0 = 0; k0 < DMODEL; k0 += 32) {
            s16x8 af = *(const s16x8*)(Omb + (size_t)(n0 + col) * DMODEL + k0 + quad * 8);
#pragma unroll
            for (int t = 0; t < 2; ++t) {
                s16x8 bf = *(const s16x8*)(Wob + (size_t)(o0 + t * 16 + col) * DMODEL + k0 + quad * 8);
                acc[t] = __builtin_amdgcn_mfma_f32_16x16x32_bf16(af, bf, acc[t], 0, 0, 0);
            }
        }
#pragma unroll
        for (int t = 0; t < 2; ++t) {
            int o = o0 + t * 16 + col;
            float bv = bo[o];
#pragma unroll
            for (int r = 0; r < 4; ++r)
                sH[(quad * 4 + r) * SH_S + o] = acc[t][r] + bv;
        }
    }
    __syncthreads();

    // ---- LN1: y1 = LN(x + h); 8 f32/thread in regs, bf16 -> sY ----
    float y1v[8];
    {
        const float* xp = X + (size_t)n_ln * DMODEL + c8;
        float v[8];
        float s = 0.f;
#pragma unroll
        for (int j = 0; j < 2; ++j) {
            float4 xv = ((const float4*)xp)[j];
            float4 hv = *(const float4*)&sH[rr_ * SH_S + c8 + j * 4];
            v[j * 4 + 0] = xv.x + hv.x; v[j * 4 + 1] = xv.y + hv.y;
            v[j * 4 + 2] = xv.z + hv.z; v[j * 4 + 3] = xv.w + hv.w;
            s += v[j * 4] + v[j * 4 + 1] + v[j * 4 + 2] + v[j * 4 + 3];
        }
#pragma unroll
        for (int m = 1; m < 32; m <<= 1) s += __shfl_xor(s, m, 64);
        float mean = s * (1.f / 256.f);
        float q = 0.f;
#pragma unroll
        for (int i = 0; i < 8; ++i) { v[i] -= mean; q += v[i] * v[i]; }
#pragma unroll
        for (int m = 1; m < 32; m <<= 1) q += __shfl_xor(q, m, 64);
        float rstd = rsqrtf(q * (1.f / 256.f) + 1e-5f);
        const float* gp = g1 + c8;
        const float* bp = be1 + c8;
        s16x8 w;
#pragma unroll
        for (int j = 0; j < 2; ++j) {
            float4 gv = ((const float4*)gp)[j];
            float4 bev = ((const float4*)bp)[j];
            float a0 = v[j * 4 + 0] * rstd * gv.x + bev.x;
            float a1 = v[j * 4 + 1] * rstd * gv.y + bev.y;
            float a2 = v[j * 4 + 2] * rstd * gv.z + bev.z;
            float a3 = v[j * 4 + 3] * rstd * gv.w + bev.w;
            y1v[j * 4 + 0] = a0; y1v[j * 4 + 1] = a1;
            y1v[j * 4 + 2] = a2; y1v[j * 4 + 3] = a3;
            *((unsigned*)&w + j * 2 + 0) = pk_bf16(a0, a1);
            *((unsigned*)&w + j * 2 + 1) = pk_bf16(a2, a3);
        }
        *(s16x8*)&sY[rr_ * SY_S + c8] = w;
    }
    __syncthreads();

    // ---- Stage B: relu(y1 · W1^T + b1) -> sR (wave: 16 x 64) ----
    {
        const int o0 = wv * 64;
        f32x4 acc[4] = {zero, zero, zero, zero};
#pragma unroll
        for (int k0 = 0; k0 < DMODEL; k0 += 32) {
            s16x8 af = *(const s16x8*)&sY[col * SY_S + k0 + quad * 8];
#pragma unroll
            for (int t = 0; t < 4; ++t) {
                s16x8 bf = *(const s16x8*)(W1b + (size_t)(o0 + t * 16 + col) * DMODEL + k0 + quad * 8);
                acc[t] = __builtin_amdgcn_mfma_f32_16x16x32_bf16(af, bf, acc[t], 0, 0, 0);
            }
        }
#pragma unroll
        for (int t = 0; t < 4; ++t) {
            int o = o0 + t * 16 + col;
            float bv = b1[o];
#pragma unroll
            for (int r = 0; r < 4; ++r)
                sR[(quad * 4 + r) * SR_S + o] = bf16r(fmaxf(acc[t][r] + bv, 0.f));
        }
    }
    __syncthreads();

    // ---- Stage C: t2 = r · W2^T + b2 (wave: 16 x 32, K=512) -> sH ----
    {
        const int o0 = wv * 32;
        f32x4 acc[2] = {zero, zero};
#pragma unroll
        for (int k0 = 0; k0 < 512; k0 += 32) {
            s16x8 af = *(const s16x8*)&sR[col * SR_S + k0 + quad * 8];
#pragma unroll
            for (int t = 0; t < 2; ++t) {
                s16x8 bf = *(const s16x8*)(W2b + (size_t)(o0 + t * 16 + col) * 512 + k0 + quad * 8);
                acc[t] = __builtin_amdgcn_mfma_f32_16x16x32_bf16(af, bf, acc[t], 0, 0, 0);
            }
        }
#pragma unroll
        for (int t = 0; t < 2; ++t) {
            int o = o0 + t * 16 + col;
            float bv = b2[o];
#pragma unroll
            for (int r = 0; r < 4; ++r)
                sH[(quad * 4 + r) * SH_S + o] = acc[t][r] + bv;
        }
    }
    __syncthreads();

    // ---- LN2: out = LN(y1 + t2) ----
    {
        float v[8];
        float s = 0.f;
#pragma unroll
        for (int j = 0; j < 2; ++j) {
            float4 hv = *(const float4*)&sH[rr_ * SH_S + c8 + j * 4];
            v[j * 4 + 0] = y1v[j * 4 + 0] + hv.x; v[j * 4 + 1] = y1v[j * 4 + 1] + hv.y;
            v[j * 4 + 2] = y1v[j * 4 + 2] + hv.z; v[j * 4 + 3] = y1v[j * 4 + 3] + hv.w;
            s += v[j * 4] + v[j * 4 + 1] + v[j * 4 + 2] + v[j * 4 + 3];
        }
#pragma unroll
        for (int m = 1; m < 32; m <<= 1) s += __shfl_xor(s, m, 64);
        float mean = s * (1.f / 256.f);
        float q = 0.f;
#pragma unroll
        for (int i = 0; i < 8; ++i) { v[i] -= mean; q += v[i] * v[i]; }
#pragma unroll
        for (int m = 1; m < 32; m <<= 1) q += __shfl_xor(q, m, 64);
        float rstd = rsqrtf(q * (1.f / 256.f) + 1e-5f);
        const float* gp = g2 + c8;
        const float* bp = be2 + c8;
        float* op = out + (size_t)n_ln * DMODEL + c8;
#pragma unroll
        for (int j = 0; j < 2; ++j) {
            float4 gv = ((const float4*)gp)[j];
            float4 bev = ((const float4*)bp)[j];
            float4 y;
            y.x = v[j * 4 + 0] * rstd * gv.x + bev.x;
            y.y = v[j * 4 + 1] * rstd * gv.y + bev.y;
            y.z = v[j * 4 + 2] * rstd * gv.z + bev.z;
            y.w = v[j * 4 + 3] * rstd * gv.w + bev.w;
            ((float4*)op)[j] = y;
        }
    }
}

// ---------------------------------------------------------------------------
extern "C" void kernel_launch(void* const* d_in, const int* in_sizes, int n_in,
                              void* d_out, int out_size, void* d_ws, size_t ws_size,
                              hipStream_t stream) {
    const float* x   = (const float*)d_in[0];
    const int*   adj = (const int*)d_in[1];
    const float* Wq  = (const float*)d_in[2];
    const float* Wk  = (const float*)d_in[3];
    const float* Wv  = (const float*)d_in[4];
    const float* bq  = (const float*)d_in[5];
    const float* bk  = (const float*)d_in[6];
    const float* bv  = (const float*)d_in[7];
    const float* Wo  = (const float*)d_in[8];
    const float* bo  = (const float*)d_in[9];
    const float* g1  = (const float*)d_in[10];
    const float* be1 = (const float*)d_in[11];
    const float* W1  = (const float*)d_in[12];
    const float* b1  = (const float*)d_in[13];
    const float* W2  = (const float*)d_in[14];
    const float* b2  = (const float*)d_in[15];
    const float* g2  = (const float*)d_in[16];
    const float* be2 = (const float*)d_in[17];
    float* out = (float*)d_out;

    char* p = (char*)d_ws;
    unsigned* mask = (unsigned*)p; p += (size_t)NROWS * 128 * 4;   //  2 MB
    short* Wb    = (short*)p;      p += (size_t)327680 * 2;        // .64 MB
    short* Wqkvb = (short*)p;      p += (size_t)196608 * 2;        // .39 MB
    short* Xb    = (short*)p;      p += (size_t)NM * 2;            //  2 MB
    short* Qb    = (short*)p;      p += (size_t)NM * 2;            //  2 MB
    short* Kb    = (short*)p;      p += (size_t)NM * 2;            //  2 MB
    short* Vswz  = (short*)p;      p += (size_t)NM * 2;            //  2 MB
    short* Omb   = (short*)p;      p += (size_t)NM * 2;            //  2 MB

    prep1_kernel<<<dim3(2816), dim3(256), 0, stream>>>(
        adj, mask, Wo, W1, W2, Wb, Wq, Wk, Wv, Wqkvb, x, Xb);
    prep2_kernel<<<dim3(768), dim3(256), 0, stream>>>(
        Xb, Wqkvb, bq, bk, bv, Qb, Kb, Vswz);
    attn_kernel<<<dim3(1024), dim3(256), 0, stream>>>(Qb, Kb, Vswz, mask, Omb);
    mega_kernel<<<dim3(256), dim3(512), 0, stream>>>(
        Omb, x, Wb, Wb + 65536, Wb + 196608,
        bo, g1, be1, b1, b2, g2, be2, out);
}

// Round 3
// 210.510 us; speedup vs baseline: 1.0678x; 1.0080x over previous
//
#include <hip/hip_runtime.h>
#include <hip/hip_bf16.h>

typedef __attribute__((ext_vector_type(4))) float f32x4;
typedef __attribute__((ext_vector_type(8))) short s16x8;

#define NROWS 4096
#define DMODEL 256
#define NHEAD 8
#define HDIM 32
#define OSTRIDE 33     // attn sO row
#define M2C 24.0f      // fixed softmax max (log2 domain)
#define NM (NROWS * DMODEL)
// mega-kernel LDS strides
#define SH_S 268
#define SY_S 264
#define SR_S 520

__device__ __forceinline__ short bf16r(float f) {
    union { float f; unsigned u; } v; v.f = f;
    unsigned r = v.u + 0x7fffu + ((v.u >> 16) & 1u);  // RNE
    return (short)(r >> 16);
}

__device__ __forceinline__ float fexp2(float x) {
    float r;
    asm("v_exp_f32 %0, %1" : "=v"(r) : "v"(x));
    return r;
}

__device__ __forceinline__ unsigned pk_bf16(float a, float b) {
#if __has_builtin(__builtin_amdgcn_cvt_pk_bf16_f32)
    typedef __bf16 bf2 __attribute__((ext_vector_type(2)));
    union { bf2 h; unsigned u; } c;
    c.h = __builtin_amdgcn_cvt_pk_bf16_f32(a, b);
    return c.u;
#else
    return (unsigned)(unsigned short)bf16r(a) | ((unsigned)(unsigned short)bf16r(b) << 16);
#endif
}

__device__ __forceinline__ s16x8 pack8(float4 a, float4 b) {
    s16x8 r;
    r[0] = bf16r(a.x); r[1] = bf16r(a.y); r[2] = bf16r(a.z); r[3] = bf16r(a.w);
    r[4] = bf16r(b.x); r[5] = bf16r(b.y); r[6] = bf16r(b.z); r[7] = bf16r(b.w);
    return r;
}

// ---------------------------------------------------------------------------
// Dispatch 1: adj -> bitmask [0,2048); pack Wo/W1/W2 [2048,2208);
// pack Wq/Wk/Wv [2208,2304); pack X [2304,2816). All one-shot streaming.
__global__ __launch_bounds__(256) void prep1_kernel(
        const int* __restrict__ adj, unsigned* __restrict__ mask,
        const float* __restrict__ Wo, const float* __restrict__ W1,
        const float* __restrict__ W2, short* __restrict__ Wb,
        const float* __restrict__ Wq, const float* __restrict__ Wk,
        const float* __restrict__ Wv, short* __restrict__ Wqkvb,
        const float* __restrict__ X, short* __restrict__ Xb) {
    const int b = blockIdx.x;
    const int tid = threadIdx.x;
    const int lane = tid & 63;
    if (b < 2048) {
        const int waveid = b * 4 + (tid >> 6);          // 0..8191
        int4 av[8];
        int rows[8], segs[8];
#pragma unroll
        for (int i = 0; i < 8; ++i) {
            const int task = waveid + i * 8192;          // 0..65535
            rows[i] = task >> 4; segs[i] = task & 15;
            av[i] = *(const int4*)(adj + (size_t)rows[i] * NROWS + segs[i] * 256 + lane * 4);
        }
#pragma unroll
        for (int i = 0; i < 8; ++i) {
            const int row = rows[i];
            const int c0 = segs[i] * 256 + lane * 4;
            unsigned nib = (unsigned)(av[i].x > 0 || c0 == row)
                         | ((unsigned)(av[i].y > 0 || c0 + 1 == row) << 1)
                         | ((unsigned)(av[i].z > 0 || c0 + 2 == row) << 2)
                         | ((unsigned)(av[i].w > 0 || c0 + 3 == row) << 3);
            unsigned v = nib << ((lane & 7) * 4);
            v |= __shfl_xor((int)v, 1, 64);
            v |= __shfl_xor((int)v, 2, 64);
            v |= __shfl_xor((int)v, 4, 64);
            if ((lane & 7) == 0)
                mask[row * 128 + segs[i] * 8 + (lane >> 3)] = v;
        }
    } else if (b < 2208) {
        int i = (b - 2048) * 2048 + tid * 8;
        const float* src; int off;
        if (i < 65536)       { src = Wo; off = i; }
        else if (i < 196608) { src = W1; off = i - 65536; }
        else                 { src = W2; off = i - 196608; }
        *(s16x8*)(Wb + i) = pack8(*(const float4*)(src + off), *(const float4*)(src + off + 4));
    } else if (b < 2304) {
        int i = (b - 2208) * 2048 + tid * 8;
        const float* src; int off;
        if (i < 65536)       { src = Wq; off = i; }
        else if (i < 131072) { src = Wk; off = i - 65536; }
        else                 { src = Wv; off = i - 131072; }
        *(s16x8*)(Wqkvb + i) = pack8(*(const float4*)(src + off), *(const float4*)(src + off + 4));
    } else {
        int i = (b - 2304) * 2048 + tid * 8;
        *(s16x8*)(Xb + i) = pack8(*(const float4*)(X + i), *(const float4*)(X + i + 4));
    }
}

// ---------------------------------------------------------------------------
// Dispatch 2: QKV GEMM from pre-packed bf16 X and [Wq;Wk;Wv]; V written
// PRE-SWIZZLED in 16x16 MFMA A-frag order with pi-permuted key slots:
// slot (quad*8+j) holds key quad*4 + (j&3) + 16*(j>>2). This makes the attn
// P repack purely in-lane (no LDS round-trip).
__global__ __launch_bounds__(256) void prep2_kernel(
        const short* __restrict__ Xb, const short* __restrict__ Wqkvb,
        const float* __restrict__ bq, const float* __restrict__ bk,
        const float* __restrict__ bv,
        short* __restrict__ Qb, short* __restrict__ Kb,
        short* __restrict__ Vswz) {
    __shared__ short sT[64 * 72];   // V-tile staging [hd_local][key_local]
    const int b = blockIdx.x;
    const int tid = threadIdx.x;
    const int lane = tid & 63;
    const int wv = tid >> 6;
    const int quad = lane >> 4, col = lane & 15;
    const int bx = b & 63, by = b >> 6;           // by 0..11
    const int o0 = by * 64;                        // 0..704 (row into [Wq;Wk;Wv])
    const int z = o0 >> 8;
    const float* bias = (z == 0) ? bq : (z == 1 ? bk : bv);
    const int ow0 = o0 & 255;
    const int n0 = bx * 64 + wv * 16;
    const float QSC = 0.25505653437397888f;        // log2e / sqrt(32)

    f32x4 zero = {0.f, 0.f, 0.f, 0.f};
    f32x4 acc[4] = {zero, zero, zero, zero};
    const short* ap = Xb + (size_t)(n0 + col) * DMODEL + quad * 8;
#pragma unroll
    for (int k0 = 0; k0 < DMODEL; k0 += 32) {
        s16x8 af = *(const s16x8*)(ap + k0);
#pragma unroll
        for (int t = 0; t < 4; ++t) {
            s16x8 bf = *(const s16x8*)(Wqkvb + (size_t)(o0 + t * 16 + col) * DMODEL + quad * 8 + k0);
            acc[t] = __builtin_amdgcn_mfma_f32_16x16x32_bf16(af, bf, acc[t], 0, 0, 0);
        }
    }
    if (z != 2) {
#pragma unroll
        for (int t = 0; t < 4; ++t) {
            const int oo = ow0 + t * 16 + col;
            float bvv = bias[oo];
#pragma unroll
            for (int r = 0; r < 4; ++r) {
                int n = n0 + quad * 4 + r;
                float v = acc[t][r] + bvv;
                if (z == 0) Qb[(size_t)n * DMODEL + oo] = bf16r(v * QSC);
                else        Kb[(size_t)(oo >> 5) * NROWS * HDIM + (size_t)n * HDIM + (oo & 31)] = bf16r(v);
            }
        }
    } else {
        // V: stage [hd_local 0..63][key_local 0..63] tile in LDS.
#pragma unroll
        for (int t = 0; t < 4; ++t) {
            const int oot = t * 16 + col;
            float bvv = bias[ow0 + oot];
#pragma unroll
            for (int r = 0; r < 4; ++r) {
                int nn = wv * 16 + quad * 4 + r;
                sT[oot * 72 + nn] = bf16r(acc[t][r] + bvv);
            }
        }
        __syncthreads();
        // Emit swizzled frags: frag f = (lh, hdh, kh); lane L, slot j holds
        // V^T[lh*32+hdh*16+(L&15)][kh*32 + pi((L>>4)*8+j)],
        // pi(q*8+j) = q*4 + (j&3) + 16*(j>>2): two 4-key runs 16 apart.
        const int f = tid >> 5;                 // 0..7
        const int lh = f >> 2, hdh = (f >> 1) & 1, kh = f & 1;
        const int L0 = (tid & 31) * 2;
        const int hgl = (ow0 >> 5) + lh;        // global head
        short* dst = Vswz + (((size_t)(hgl * 64 + bx) * 4 + hdh * 2 + kh) * 512);
#pragma unroll
        for (int e = 0; e < 2; ++e) {
            int L = L0 + e;
            int hd_local = lh * 32 + hdh * 16 + (L & 15);
            int base = kh * 32 + (L >> 4) * 4;
            uint2 lo = *(const uint2*)&sT[hd_local * 72 + base];        // keys base..+3   (j=0..3)
            uint2 hi = *(const uint2*)&sT[hd_local * 72 + base + 16];   // keys base+16..+19 (j=4..7)
            *(uint2*)(dst + L * 8) = lo;
            *(uint2*)(dst + L * 8 + 4) = hi;
        }
    }
}

// ---------------------------------------------------------------------------
// Dispatch 3: flash attention, fully register-resident P path. Block = (32 q,
// head), grid 1024; wave w owns keys [w*1024, +1024), 16 iters of 64 keys.
// QK^T lane (quad,col) holds keys t*16+quad*4+r for q=col; V-frags are
// pi-slot-permuted so the masked packed words ARE the PV B-frag in register:
// P0 = {t0,t1}, P1 = {t2,t3}. No LDS in the main loop except broadcast LUT.
__global__ __launch_bounds__(256) void attn_kernel(const short* __restrict__ Qb,
                                                   const short* __restrict__ Kb,
                                                   const short* __restrict__ Vswz,
                                                   const unsigned* __restrict__ mask,
                                                   short* __restrict__ Om) {
    __shared__ float sO[4][HDIM][OSTRIDE];
    __shared__ float sl[4][32];
    __shared__ __align__(16) unsigned lut2[32];  // [nib][2]: AND masks for 2 packed pairs

    const int tid = threadIdx.x;
    const int wv = tid >> 6, lane = tid & 63;
    const int quad = lane >> 4, col = lane & 15;
    const int h = blockIdx.x & 7;
    const int q0 = (blockIdx.x >> 3) * 32;
    const int kw = wv * 1024;

    if (tid < 32) {
        int i = tid >> 1;
        unsigned b0 = (tid & 1) ? ((i >> 2) & 1u) : (i & 1u);
        unsigned b1 = (tid & 1) ? ((i >> 3) & 1u) : ((i >> 1) & 1u);
        lut2[tid] = (b0 ? 0xFFFFu : 0u) | (b1 ? 0xFFFF0000u : 0u);
    }
    __syncthreads();

    s16x8 qf[2];
    qf[0] = *(const s16x8*)(Qb + (size_t)(q0 + col) * DMODEL + h * HDIM + quad * 8);
    qf[1] = *(const s16x8*)(Qb + (size_t)(q0 + 16 + col) * DMODEL + h * HDIM + quad * 8);

    const short* kp = Kb + (size_t)h * NROWS * HDIM + (size_t)(kw + col) * HDIM + quad * 8;
    const short* vbase = Vswz + ((size_t)(h * 64 + (kw >> 6)) * 4) * 512 + lane * 8;
    const unsigned* mp0 = mask + (size_t)(q0 + col) * 128 + (kw >> 5);
    const unsigned* mp1 = mp0 + 16 * 128;

    const short onev = (col == 0) ? (short)0x3F80 : (short)0;
    const s16x8 ones = {onev, onev, onev, onev, onev, onev, onev, onev};

    f32x4 zero = {0.f, 0.f, 0.f, 0.f};
    f32x4 acc[2][2] = {{zero, zero}, {zero, zero}};
    f32x4 lacc[2] = {zero, zero};
    const f32x4 cinit = {-M2C, -M2C, -M2C, -M2C};
    const int sh_lo = quad * 4, sh_hi = 16 + quad * 4;
    const char* lb = (const char*)lut2;

#pragma unroll 2
    for (int it = 0; it < 16; ++it) {
        const short* k = kp + it * 64 * HDIM;
        s16x8 kf0 = *(const s16x8*)(k);
        s16x8 kf1 = *(const s16x8*)(k + 16 * HDIM);
        s16x8 kf2 = *(const s16x8*)(k + 32 * HDIM);
        s16x8 kf3 = *(const s16x8*)(k + 48 * HDIM);
        uint2 w0 = *(const uint2*)(mp0 + it * 2);
        uint2 w1 = *(const uint2*)(mp1 + it * 2);
        const short* vb = vbase + it * 4 * 512;
        s16x8 vf00 = *(const s16x8*)(vb);             // hd 0-15,  keys 0-31 (pi slots)
        s16x8 vf01 = *(const s16x8*)(vb + 512);       // hd 0-15,  keys 32-63
        s16x8 vf10 = *(const s16x8*)(vb + 1024);      // hd 16-31, keys 0-31
        s16x8 vf11 = *(const s16x8*)(vb + 1536);      // hd 16-31, keys 32-63

#pragma unroll
        for (int qs = 0; qs < 2; ++qs) {
            const unsigned wx = qs ? w1.x : w0.x;     // keys 0..31 of tile
            const unsigned wy = qs ? w1.y : w0.y;     // keys 32..63
            // LUT AND-masks: st[t][r] = key t*16 + quad*4 + r
            uint2 m0 = *(const uint2*)(lb + (((wx >> sh_lo) & 0xF) << 3));
            uint2 m1 = *(const uint2*)(lb + (((wx >> sh_hi) & 0xF) << 3));
            uint2 m2 = *(const uint2*)(lb + (((wy >> sh_lo) & 0xF) << 3));
            uint2 m3 = *(const uint2*)(lb + (((wy >> sh_hi) & 0xF) << 3));

            f32x4 st[4];
            st[0] = __builtin_amdgcn_mfma_f32_16x16x32_bf16(kf0, qf[qs], cinit, 0, 0, 0);
            st[1] = __builtin_amdgcn_mfma_f32_16x16x32_bf16(kf1, qf[qs], cinit, 0, 0, 0);
            st[2] = __builtin_amdgcn_mfma_f32_16x16x32_bf16(kf2, qf[qs], cinit, 0, 0, 0);
            st[3] = __builtin_amdgcn_mfma_f32_16x16x32_bf16(kf3, qf[qs], cinit, 0, 0, 0);

            // masked packed words ARE the PV B-frags (pi-slot order)
            union { unsigned u[4]; s16x8 v; } P0, P1;
            P0.u[0] = pk_bf16(fexp2(st[0][0]), fexp2(st[0][1])) & m0.x;
            P0.u[1] = pk_bf16(fexp2(st[0][2]), fexp2(st[0][3])) & m0.y;
            P0.u[2] = pk_bf16(fexp2(st[1][0]), fexp2(st[1][1])) & m1.x;
            P0.u[3] = pk_bf16(fexp2(st[1][2]), fexp2(st[1][3])) & m1.y;
            P1.u[0] = pk_bf16(fexp2(st[2][0]), fexp2(st[2][1])) & m2.x;
            P1.u[1] = pk_bf16(fexp2(st[2][2]), fexp2(st[2][3])) & m2.y;
            P1.u[2] = pk_bf16(fexp2(st[3][0]), fexp2(st[3][1])) & m3.x;
            P1.u[3] = pk_bf16(fexp2(st[3][2]), fexp2(st[3][3])) & m3.y;

            acc[qs][0] = __builtin_amdgcn_mfma_f32_16x16x32_bf16(vf00, P0.v, acc[qs][0], 0, 0, 0);
            acc[qs][0] = __builtin_amdgcn_mfma_f32_16x16x32_bf16(vf01, P1.v, acc[qs][0], 0, 0, 0);
            acc[qs][1] = __builtin_amdgcn_mfma_f32_16x16x32_bf16(vf10, P0.v, acc[qs][1], 0, 0, 0);
            acc[qs][1] = __builtin_amdgcn_mfma_f32_16x16x32_bf16(vf11, P1.v, acc[qs][1], 0, 0, 0);
            lacc[qs] = __builtin_amdgcn_mfma_f32_16x16x32_bf16(ones, P0.v, lacc[qs], 0, 0, 0);
            lacc[qs] = __builtin_amdgcn_mfma_f32_16x16x32_bf16(ones, P1.v, lacc[qs], 0, 0, 0);
        }
    }

#pragma unroll
    for (int qs = 0; qs < 2; ++qs) {
        if (lane < 16) sl[wv][qs * 16 + col] = lacc[qs][0];
#pragma unroll
        for (int rr = 0; rr < 4; ++rr) {
            sO[wv][quad * 4 + rr][qs * 16 + col]      = acc[qs][0][rr];
            sO[wv][16 + quad * 4 + rr][qs * 16 + col] = acc[qs][1][rr];
        }
    }
    __syncthreads();

    // merge the 4 key-partitions, normalize, write bf16
    const int q = tid >> 3, hd0 = (tid & 7) * 4;
    float l = sl[0][q] + sl[1][q] + sl[2][q] + sl[3][q];
    float inv = 1.f / l;   // diagonal always allowed -> l > 0
    float4 ov;
    ov.x = sO[0][hd0][q]     + sO[1][hd0][q]     + sO[2][hd0][q]     + sO[3][hd0][q];
    ov.y = sO[0][hd0 + 1][q] + sO[1][hd0 + 1][q] + sO[2][hd0 + 1][q] + sO[3][hd0 + 1][q];
    ov.z = sO[0][hd0 + 2][q] + sO[1][hd0 + 2][q] + sO[2][hd0 + 2][q] + sO[3][hd0 + 2][q];
    ov.w = sO[0][hd0 + 3][q] + sO[1][hd0 + 3][q] + sO[2][hd0 + 3][q] + sO[3][hd0 + 3][q];
    uint2 ob;
    ob.x = pk_bf16(ov.x * inv, ov.y * inv);
    ob.y = pk_bf16(ov.z * inv, ov.w * inv);
    *(uint2*)(Om + (size_t)(q0 + q) * DMODEL + h * HDIM + hd0) = ob;
}

// ---------------------------------------------------------------------------
// Dispatch 4: post-attention chain per 16-row stripe, 512 threads/block.
__global__ __launch_bounds__(512) void mega_kernel(
        const short* __restrict__ Omb,
        const float* __restrict__ X,
        const short* __restrict__ Wob, const short* __restrict__ W1b,
        const short* __restrict__ W2b,
        const float* __restrict__ bo,
        const float* __restrict__ g1, const float* __restrict__ be1,
        const float* __restrict__ b1, const float* __restrict__ b2,
        const float* __restrict__ g2, const float* __restrict__ be2,
        float* __restrict__ out) {
    __shared__ short sR[16 * SR_S];
    __shared__ float sH[16 * SH_S];
    __shared__ short sY[16 * SY_S];

    const int tid = threadIdx.x;
    const int wv = tid >> 6, lane = tid & 63;
    const int quad = lane >> 4, col = lane & 15;
    const int n0 = blockIdx.x * 16;
    const int rr_ = tid >> 5, c8 = (tid & 31) * 8;
    const int n_ln = n0 + rr_;
    f32x4 zero = {0.f, 0.f, 0.f, 0.f};

    // ---- Stage A2: h = O · Wo^T + bo (wave: 16 x 32; A from global) ----
    {
        const int o0 = wv * 32;
        f32x4 acc[2] = {zero, zero};
#pragma unroll
        for (int k0 = 0; k0 < DMODEL; k0 += 32) {
            s16x8 af = *(const s16x8*)(Omb + (size_t)(n0 + col) * DMODEL + k0 + quad * 8);
#pragma unroll
            for (int t = 0; t < 2; ++t) {
                s16x8 bf = *(const s16x8*)(Wob + (size_t)(o0 + t * 16 + col) * DMODEL + k0 + quad * 8);
                acc[t] = __builtin_amdgcn_mfma_f32_16x16x32_bf16(af, bf, acc[t], 0, 0, 0);
            }
        }
#pragma unroll
        for (int t = 0; t < 2; ++t) {
            int o = o0 + t * 16 + col;
            float bv = bo[o];
#pragma unroll
            for (int r = 0; r < 4; ++r)
                sH[(quad * 4 + r) * SH_S + o] = acc[t][r] + bv;
        }
    }
    __syncthreads();

    // ---- LN1: y1 = LN(x + h); 8 f32/thread in regs, bf16 -> sY ----
    float y1v[8];
    {
        const float* xp = X + (size_t)n_ln * DMODEL + c8;
        float v[8];
        float s = 0.f;
#pragma unroll
        for (int j = 0; j < 2; ++j) {
            float4 xv = ((const float4*)xp)[j];
            float4 hv = *(const float4*)&sH[rr_ * SH_S + c8 + j * 4];
            v[j * 4 + 0] = xv.x + hv.x; v[j * 4 + 1] = xv.y + hv.y;
            v[j * 4 + 2] = xv.z + hv.z; v[j * 4 + 3] = xv.w + hv.w;
            s += v[j * 4] + v[j * 4 + 1] + v[j * 4 + 2] + v[j * 4 + 3];
        }
#pragma unroll
        for (int m = 1; m < 32; m <<= 1) s += __shfl_xor(s, m, 64);
        float mean = s * (1.f / 256.f);
        float q = 0.f;
#pragma unroll
        for (int i = 0; i < 8; ++i) { v[i] -= mean; q += v[i] * v[i]; }
#pragma unroll
        for (int m = 1; m < 32; m <<= 1) q += __shfl_xor(q, m, 64);
        float rstd = rsqrtf(q * (1.f / 256.f) + 1e-5f);
        const float* gp = g1 + c8;
        const float* bp = be1 + c8;
        s16x8 w;
#pragma unroll
        for (int j = 0; j < 2; ++j) {
            float4 gv = ((const float4*)gp)[j];
            float4 bev = ((const float4*)bp)[j];
            float a0 = v[j * 4 + 0] * rstd * gv.x + bev.x;
            float a1 = v[j * 4 + 1] * rstd * gv.y + bev.y;
            float a2 = v[j * 4 + 2] * rstd * gv.z + bev.z;
            float a3 = v[j * 4 + 3] * rstd * gv.w + bev.w;
            y1v[j * 4 + 0] = a0; y1v[j * 4 + 1] = a1;
            y1v[j * 4 + 2] = a2; y1v[j * 4 + 3] = a3;
            *((unsigned*)&w + j * 2 + 0) = pk_bf16(a0, a1);
            *((unsigned*)&w + j * 2 + 1) = pk_bf16(a2, a3);
        }
        *(s16x8*)&sY[rr_ * SY_S + c8] = w;
    }
    __syncthreads();

    // ---- Stage B: relu(y1 · W1^T + b1) -> sR (wave: 16 x 64) ----
    {
        const int o0 = wv * 64;
        f32x4 acc[4] = {zero, zero, zero, zero};
#pragma unroll
        for (int k0 = 0; k0 < DMODEL; k0 += 32) {
            s16x8 af = *(const s16x8*)&sY[col * SY_S + k0 + quad * 8];
#pragma unroll
            for (int t = 0; t < 4; ++t) {
                s16x8 bf = *(const s16x8*)(W1b + (size_t)(o0 + t * 16 + col) * DMODEL + k0 + quad * 8);
                acc[t] = __builtin_amdgcn_mfma_f32_16x16x32_bf16(af, bf, acc[t], 0, 0, 0);
            }
        }
#pragma unroll
        for (int t = 0; t < 4; ++t) {
            int o = o0 + t * 16 + col;
            float bv = b1[o];
#pragma unroll
            for (int r = 0; r < 4; ++r)
                sR[(quad * 4 + r) * SR_S + o] = bf16r(fmaxf(acc[t][r] + bv, 0.f));
        }
    }
    __syncthreads();

    // ---- Stage C: t2 = r · W2^T + b2 (wave: 16 x 32, K=512) -> sH ----
    {
        const int o0 = wv * 32;
        f32x4 acc[2] = {zero, zero};
#pragma unroll
        for (int k0 = 0; k0 < 512; k0 += 32) {
            s16x8 af = *(const s16x8*)&sR[col * SR_S + k0 + quad * 8];
#pragma unroll
            for (int t = 0; t < 2; ++t) {
                s16x8 bf = *(const s16x8*)(W2b + (size_t)(o0 + t * 16 + col) * 512 + k0 + quad * 8);
                acc[t] = __builtin_amdgcn_mfma_f32_16x16x32_bf16(af, bf, acc[t], 0, 0, 0);
            }
        }
#pragma unroll
        for (int t = 0; t < 2; ++t) {
            int o = o0 + t * 16 + col;
            float bv = b2[o];
#pragma unroll
            for (int r = 0; r < 4; ++r)
                sH[(quad * 4 + r) * SH_S + o] = acc[t][r] + bv;
        }
    }
    __syncthreads();

    // ---- LN2: out = LN(y1 + t2) ----
    {
        float v[8];
        float s = 0.f;
#pragma unroll
        for (int j = 0; j < 2; ++j) {
            float4 hv = *(const float4*)&sH[rr_ * SH_S + c8 + j * 4];
            v[j * 4 + 0] = y1v[j * 4 + 0] + hv.x; v[j * 4 + 1] = y1v[j * 4 + 1] + hv.y;
            v[j * 4 + 2] = y1v[j * 4 + 2] + hv.z; v[j * 4 + 3] = y1v[j * 4 + 3] + hv.w;
            s += v[j * 4] + v[j * 4 + 1] + v[j * 4 + 2] + v[j * 4 + 3];
        }
#pragma unroll
        for (int m = 1; m < 32; m <<= 1) s += __shfl_xor(s, m, 64);
        float mean = s * (1.f / 256.f);
        float q = 0.f;
#pragma unroll
        for (int i = 0; i < 8; ++i) { v[i] -= mean; q += v[i] * v[i]; }
#pragma unroll
        for (int m = 1; m < 32; m <<= 1) q += __shfl_xor(q, m, 64);
        float rstd = rsqrtf(q * (1.f / 256.f) + 1e-5f);
        const float* gp = g2 + c8;
        const float* bp = be2 + c8;
        float* op = out + (size_t)n_ln * DMODEL + c8;
#pragma unroll
        for (int j = 0; j < 2; ++j) {
            float4 gv = ((const float4*)gp)[j];
            float4 bev = ((const float4*)bp)[j];
            float4 y;
            y.x = v[j * 4 + 0] * rstd * gv.x + bev.x;
            y.y = v[j * 4 + 1] * rstd * gv.y + bev.y;
            y.z = v[j * 4 + 2] * rstd * gv.z + bev.z;
            y.w = v[j * 4 + 3] * rstd * gv.w + bev.w;
            ((float4*)op)[j] = y;
        }
    }
}

// ---------------------------------------------------------------------------
extern "C" void kernel_launch(void* const* d_in, const int* in_sizes, int n_in,
                              void* d_out, int out_size, void* d_ws, size_t ws_size,
                              hipStream_t stream) {
    const float* x   = (const float*)d_in[0];
    const int*   adj = (const int*)d_in[1];
    const float* Wq  = (const float*)d_in[2];
    const float* Wk  = (const float*)d_in[3];
    const float* Wv  = (const float*)d_in[4];
    const float* bq  = (const float*)d_in[5];
    const float* bk  = (const float*)d_in[6];
    const float* bv  = (const float*)d_in[7];
    const float* Wo  = (const float*)d_in[8];
    const float* bo  = (const float*)d_in[9];
    const float* g1  = (const float*)d_in[10];
    const float* be1 = (const float*)d_in[11];
    const float* W1  = (const float*)d_in[12];
    const float* b1  = (const float*)d_in[13];
    const float* W2  = (const float*)d_in[14];
    const float* b2  = (const float*)d_in[15];
    const float* g2  = (const float*)d_in[16];
    const float* be2 = (const float*)d_in[17];
    float* out = (float*)d_out;

    char* p = (char*)d_ws;
    unsigned* mask = (unsigned*)p; p += (size_t)NROWS * 128 * 4;   //  2 MB
    short* Wb    = (short*)p;      p += (size_t)327680 * 2;        // .64 MB
    short* Wqkvb = (short*)p;      p += (size_t)196608 * 2;        // .39 MB
    short* Xb    = (short*)p;      p += (size_t)NM * 2;            //  2 MB
    short* Qb    = (short*)p;      p += (size_t)NM * 2;            //  2 MB
    short* Kb    = (short*)p;      p += (size_t)NM * 2;            //  2 MB
    short* Vswz  = (short*)p;      p += (size_t)NM * 2;            //  2 MB
    short* Omb   = (short*)p;      p += (size_t)NM * 2;            //  2 MB

    prep1_kernel<<<dim3(2816), dim3(256), 0, stream>>>(
        adj, mask, Wo, W1, W2, Wb, Wq, Wk, Wv, Wqkvb, x, Xb);
    prep2_kernel<<<dim3(768), dim3(256), 0, stream>>>(
        Xb, Wqkvb, bq, bk, bv, Qb, Kb, Vswz);
    attn_kernel<<<dim3(1024), dim3(256), 0, stream>>>(Qb, Kb, Vswz, mask, Omb);
    mega_kernel<<<dim3(256), dim3(512), 0, stream>>>(
        Omb, x, Wb, Wb + 65536, Wb + 196608,
        bo, g1, be1, b1, b2, g2, be2, out);
}